// Round 3
// baseline (141.590 us; speedup 1.0000x reference)
//
#include <hip/hip_runtime.h>
#include <float.h>

// Batched 1D linear interpolation with clamped extrapolation.
// t: [B,N] sorted fp32, v: [B,N] fp32, r: [B,M] fp32 -> out: [B,M] fp32
constexpr int B = 2048;
constexpr int N = 4096;
constexpr int M = 4096;
constexpr int K = 4080;  // LDS: st (N+8)*4 + sv N*4 + lut K*2 = 16416+16384+8160 = 40960 B
constexpr int T = 512;   // 4 blocks/CU x 8 waves = 32 waves/CU

__global__ __launch_bounds__(T, 8) void interp_kernel(
    const float* __restrict__ t,
    const float* __restrict__ v,
    const float* __restrict__ r,
    float* __restrict__ out) {
    __shared__ __align__(16) float st[N + 8];       // st[N..N+7] = +inf sentinels (window-8 scan)
    __shared__ __align__(16) float sv[N];
    __shared__ unsigned short lut[K];               // lut[k] = first j with (int)(t[j]*K) >= k; else N

    const int b = blockIdx.x;
    const float* tb = t + (size_t)b * N;
    const float* vb = v + (size_t)b * N;
    const float* rb = r + (size_t)b * M;
    float* ob = out + (size_t)b * M;

    // Queries first: HBM latency hides under staging + lut fill.
    const float4* r4 = (const float4*)rb;
    const int ia = threadIdx.x;
    const int ib = ia + T;
    const float4 qa = r4[ia];
    const float4 qb = r4[ib];

    // Stage t/v into LDS (coalesced float4); plant window sentinels.
    for (int i = threadIdx.x; i < N / 4; i += T) {
        ((float4*)st)[i] = ((const float4*)tb)[i];
        ((float4*)sv)[i] = ((const float4*)vb)[i];
    }
    if (threadIdx.x < 8) st[N + threadIdx.x] = FLT_MAX;

    // Lut fill from GLOBAL t (L1-hot: this block just streamed it), so it does
    // not depend on the LDS staging -> single barrier for the whole prologue.
    // Element j covers buckets (bucket(t[j-1]), bucket(t[j])]; disjoint -> no
    // races; the j==N-1 owner also fills the tail with N (replaces init pass).
    for (int j = threadIdx.x; j < N; j += T) {
        const float tj = tb[j];
        int khi = (int)(tj * (float)K);
        if (khi > K - 1) khi = K - 1;
        const int klo = (j > 0) ? (int)(tb[j - 1] * (float)K) + 1 : 0;
        for (int k = klo; k <= khi; ++k) lut[k] = (unsigned short)j;
        if (j == N - 1)
            for (int k = khi + 1; k < K; ++k) lut[k] = (unsigned short)N;
    }
    __syncthreads();

    const float tfirst = st[0];
    const float vfirst = sv[0];
    const float tlast = st[N - 1];
    const float vlast = sv[N - 1];

    float q[8] = {qa.x, qa.y, qa.z, qa.w, qb.x, qb.y, qb.z, qb.w};
    int lo[8];
    float w[8];

    // Phase 1: all 8 lut loads issued together.
    // Invariant: t[lut[k]-1] has bucket < k <= bucket(q) -> t[lo-1] <= q.
    #pragma unroll
    for (int j = 0; j < 8; ++j) {
        int k = (int)(q[j] * (float)K);
        k = k < 0 ? 0 : (k > K - 1 ? K - 1 : k);
        lo[j] = lut[k];
    }
    // Phase 2: branchless binary search over window 8 (+4,+2,+1), phase-batched
    // for 8-wide MLP. Exact for <=8 pts/window; P(wave fallback) ~ 0.5%.
    #pragma unroll
    for (int j = 0; j < 8; ++j) w[j] = st[lo[j] + 3];
    #pragma unroll
    for (int j = 0; j < 8; ++j) lo[j] += (w[j] <= q[j]) ? 4 : 0;
    #pragma unroll
    for (int j = 0; j < 8; ++j) w[j] = st[lo[j] + 1];
    #pragma unroll
    for (int j = 0; j < 8; ++j) lo[j] += (w[j] <= q[j]) ? 2 : 0;
    #pragma unroll
    for (int j = 0; j < 8; ++j) {
        // Pair read (ds_read2_b32): the post-step st[lo] comes for free, so the
        // dense-bucket fallback check costs no extra LDS read.
        const float ta = st[lo[j]];
        const float tb1 = st[lo[j] + 1];
        const bool c = ta <= q[j];
        lo[j] += c ? 1 : 0;
        const float tcur = c ? tb1 : ta;  // == st[lo[j]] after the step
        if (tcur <= q[j]) {               // rare: >8 points in window
            int l = lo[j] + 1;
            while (st[l] <= q[j]) ++l;    // sentinels bound the walk
            lo[j] = l;
        }
    }
    // Phase 3: final pair fetches (ds_read2_b32 x2) + interp math (fast rcp).
    float o[8];
    #pragma unroll
    for (int j = 0; j < 8; ++j) {
        const int idx = lo[j] < 1 ? 1 : (lo[j] > N - 1 ? N - 1 : lo[j]);
        const float t0 = st[idx - 1];
        const float t1 = st[idx];
        const float v0 = sv[idx - 1];
        const float v1 = sv[idx];
        const float d = t1 - t0;
        const float rden = __builtin_amdgcn_rcpf(d == 0.0f ? 1.0f : d);
        float oo = v0 + (q[j] - t0) * rden * (v1 - v0);
        oo = (q[j] < tfirst) ? vfirst : oo;
        oo = (q[j] > tlast) ? vlast : oo;
        o[j] = oo;
    }
    float4* o4 = (float4*)ob;
    o4[ia] = make_float4(o[0], o[1], o[2], o[3]);
    o4[ib] = make_float4(o[4], o[5], o[6], o[7]);
}

extern "C" void kernel_launch(void* const* d_in, const int* in_sizes, int n_in,
                              void* d_out, int out_size, void* d_ws, size_t ws_size,
                              hipStream_t stream) {
    const float* t = (const float*)d_in[0];
    const float* v = (const float*)d_in[1];
    const float* r = (const float*)d_in[2];
    float* out = (float*)d_out;
    interp_kernel<<<B, T, 0, stream>>>(t, v, r, out);
}